// Round 3
// baseline (34.846 us; speedup 1.0000x reference)
//
#include <hip/hip_runtime.h>
#include <stdint.h>

// Problem constants (from reference setup_inputs)
#define NVARS   128
#define EMBED   256
#define L0      1024
#define NSTEPS  16
#define NBATCH  64

typedef unsigned long long u64;
typedef unsigned int u32;

__device__ __forceinline__ u64 shfl_down_u64(u64 x, int off) {
    u32 lo = (u32)x, hi = (u32)(x >> 32);
    lo = __shfl_down(lo, off, 64);
    hi = __shfl_down(hi, off, 64);
    return ((u64)hi << 32) | (u64)lo;
}

// One block per batch item (64 blocks x 1024 threads).
// Phase 1: 16 waves stream the batch's 1024 rows (1 KB contiguous float4 load
//   per wave per row, 8 rows in flight), ballot-pack to 4 u64 words/row in LDS.
//   Permuted bit layout (popcount/OR are permutation-invariant; output remaps):
//     word0 (A0) = lo32(m0)|lo32(m1)<<32   word1 (A1) = lo32(m2)|lo32(m3)<<32
//     word2 (B0) = hi32(m0)|hi32(m1)<<32   word3 (B1) = hi32(m2)|hi32(m3)<<32
//   (m_c = ballot of float4 component c; lane l holds dims 4l..4l+3)
//   var v (0..127): word = 2 + ((v>>1)&1), bit = (v>>2) | ((v&1)<<5)
// Phase 2: thread t owns row t in registers; step 0 = full argmin reduction;
//   steps 1..15 = incremental fast path (appended query rows have a==0 so
//   cmin==0 and their b-masks are subsets of the running union).
__global__ __launch_bounds__(1024) void fused_kernel(const float4* __restrict__ tok4,
                                                     float* __restrict__ out) {
    __shared__ u64 s_pack[L0][4];          // 32 KiB
    __shared__ int s_c[16];
    __shared__ u64 s_o0[16], s_o1[16];
    __shared__ u64 s_rp0, s_rp1;           // pure r_0 (step 0 has 3-way output)
    __shared__ u32 s_acc[4];               // running union: qb_s growing to r_s

    const int b    = blockIdx.x;
    const int tid  = threadIdx.x;
    const int lane = tid & 63;
    const int w    = tid >> 6;             // wave 0..15

    const float4* base = tok4 + (size_t)b * L0 * 64;

    // ---- phase 1: pack 64 rows per wave ----
    for (int it = 0; it < 64; it += 8) {
        float4 v[8];
        #pragma unroll
        for (int r = 0; r < 8; ++r)
            v[r] = base[(size_t)(w * 64 + it + r) * 64 + lane];
        #pragma unroll
        for (int r = 0; r < 8; ++r) {
            u64 m0 = __ballot(v[r].x > 0.5f);
            u64 m1 = __ballot(v[r].y > 0.5f);
            u64 m2 = __ballot(v[r].z > 0.5f);
            u64 m3 = __ballot(v[r].w > 0.5f);
            u64 wd;
            if      (lane == 0) wd = (m0 & 0xffffffffull) | (m1 << 32);
            else if (lane == 1) wd = (m2 & 0xffffffffull) | (m3 << 32);
            else if (lane == 2) wd = (m0 >> 32) | (m1 & 0xffffffff00000000ull);
            else                wd = (m2 >> 32) | (m3 & 0xffffffff00000000ull);
            if (lane < 4) s_pack[w * 64 + it + r][lane] = wd;
        }
    }
    __syncthreads();

    // ---- own row into registers; qb = b-half of row 1023 (LDS broadcast) ----
    const u64 ra0 = s_pack[tid][0], ra1 = s_pack[tid][1];
    const u64 rb0 = s_pack[tid][2], rb1 = s_pack[tid][3];
    const u64 qb0 = s_pack[L0 - 1][2], qb1 = s_pack[L0 - 1][3];

    // ---- step 0: full min + argmin-OR reduction ----
    int c = __popcll(ra0 & ~qb0) + __popcll(ra1 & ~qb1);
    int cm = c; u64 o0 = rb0, o1 = rb1;
    #pragma unroll
    for (int off = 32; off; off >>= 1) {
        int c2 = __shfl_down(cm, off, 64);
        u64 p0 = shfl_down_u64(o0, off), p1 = shfl_down_u64(o1, off);
        if (c2 < cm)       { cm = c2; o0 = p0; o1 = p1; }
        else if (c2 == cm) { o0 |= p0; o1 |= p1; }
    }
    if (lane == 0) { s_c[w] = cm; s_o0[w] = o0; s_o1[w] = o1; }
    __syncthreads();
    if (tid == 0) {
        int rc = s_c[0]; u64 r0 = s_o0[0], r1 = s_o1[0];
        #pragma unroll
        for (int k = 1; k < 16; ++k) {
            if (s_c[k] < rc)       { rc = s_c[k]; r0 = s_o0[k]; r1 = s_o1[k]; }
            else if (s_c[k] == rc) { r0 |= s_o0[k]; r1 |= s_o1[k]; }
        }
        s_rp0 = r0; s_rp1 = r1;
        u64 u0 = r0 | qb0, u1 = r1 | qb1;   // qb_1
        s_acc[0] = (u32)u0; s_acc[1] = (u32)(u0 >> 32);
        s_acc[2] = (u32)u1; s_acc[3] = (u32)(u1 >> 32);
    }
    __syncthreads();

    const float TP = 0.46211715726000974f;   // tanh(0.5)
    float* ob = out + (size_t)b * NSTEPS * NVARS;
    if (tid < NVARS) {
        const int wi = (tid >> 1) & 1, bit = (tid >> 2) | ((tid & 1) << 5);
        u64 rw = wi ? s_rp1 : s_rp0;
        u64 qw = wi ? qb1 : qb0;
        ob[tid] = ((rw >> bit) & 1) ? 1.0f : (((qw >> bit) & 1) ? TP : -TP);
    }
    u64 rcur0 = (u64)s_acc[0] | ((u64)s_acc[1] << 32);   // qb_1
    u64 rcur1 = (u64)s_acc[2] | ((u64)s_acc[3] << 32);
    u64 qbp0 = qb0, qbp1 = qb1;
    __syncthreads();   // reads of s_rp/s_acc done before step-1 atomics

    // ---- steps 1..15: incremental fast path (cmin == 0 guaranteed) ----
    for (int s = 1; s < NSTEPS; ++s) {
        const u64 d0 = rcur0 & ~qbp0, d1 = rcur1 & ~qbp1;   // qb delta (uniform)
        if (d0 | d1) {
            c -= __popcll(ra0 & d0) + __popcll(ra1 & d1);
            qbp0 = rcur0; qbp1 = rcur1;
        }
        if (c == 0) {   // argmin base row: contribute its new b-bits
            u64 nb0 = rb0 & ~rcur0, nb1 = rb1 & ~rcur1;
            if ((u32)nb0)         atomicOr(&s_acc[0], (u32)nb0);
            if ((u32)(nb0 >> 32)) atomicOr(&s_acc[1], (u32)(nb0 >> 32));
            if ((u32)nb1)         atomicOr(&s_acc[2], (u32)nb1);
            if ((u32)(nb1 >> 32)) atomicOr(&s_acc[3], (u32)(nb1 >> 32));
        }
        __syncthreads();   // atomics complete
        const u64 rn0 = (u64)s_acc[0] | ((u64)s_acc[1] << 32);   // r_s
        const u64 rn1 = (u64)s_acc[2] | ((u64)s_acc[3] << 32);
        if (tid < NVARS) {
            const int wi = (tid >> 1) & 1, bit = (tid >> 2) | ((tid & 1) << 5);
            u64 rw = wi ? rn1 : rn0;
            // r_s >= qb_s: qb-bit set => r-bit set => 1.0; else qb-bit is 0 => -TP
            ob[s * NVARS + tid] = ((rw >> bit) & 1) ? 1.0f : -TP;
        }
        rcur0 = rn0; rcur1 = rn1;
        __syncthreads();   // reads done before next step's atomics
    }
}

extern "C" void kernel_launch(void* const* d_in, const int* in_sizes, int n_in,
                              void* d_out, int out_size, void* d_ws, size_t ws_size,
                              hipStream_t stream) {
    const float4* tok4 = (const float4*)d_in[0];
    float* out = (float*)d_out;
    fused_kernel<<<NBATCH, 1024, 0, stream>>>(tok4, out);
}